// Round 7
// baseline (148.787 us; speedup 1.0000x reference)
//
#include <hip/hip_runtime.h>

// Round 7: flat streaming kernel (round-4 structure, verified absmax==0) with
// a hard scheduling barrier between the load batch and the compute batch.
// Diagnosis from rounds 2/4/6: duration pinned at ~43 us regardless of
// structure => HBM-latency-bound with low memory-level parallelism (1.6-2.8
// TB/s achieved vs 6.3 achievable). Fix: force ALL ~43 VMEM loads per thread
// to issue before any consumer via __builtin_amdgcn_sched_barrier(0), keeping
// ~111 result floats live in VGPRs (3 waves/SIMD, each with its whole line
// batch outstanding).
//
// Energy collapse (verified): sum_pq coeff[p][q](Dp.Dq)
//   = 3(|u|^2+|w|^2+u.w) + (|a|^2+|b|^2+a.b), a=n1.(R1-R2), b=n2.(R1-R2), H=1.
// Adjacency (verified): quad q=(i,j), f1=tri1=i*m+j, tri2=Q+i*m+j.
//   diag : f2=tri2(i,j):   u=t1r2-t2r2, w=t1r1-t2r0; n1=N[v01], n2=N[v10]
//   horiz: f2=tri2(i-1,j): u=t1r0-t2r0, w=t1r2-t2r1; n1=N[v00], n2=N[v01]
//   vert : f2=tri2(i,j-1): u=t1r0-t2r2, w=t1r1-t2r1; n1=N[v00], n2=N[v10]

struct __attribute__((aligned(4))) F4s { float a, b, c, d; };
struct F3 { float x, y, z; };
struct R9 { float v[9]; };
struct R6 { float v[6]; };

__device__ __forceinline__ R9 load9(const float* __restrict__ p) {
    R9 r;
    F4s u0 = *(const F4s*)p;
    F4s u1 = *(const F4s*)(p + 4);
    r.v[0] = u0.a; r.v[1] = u0.b; r.v[2] = u0.c; r.v[3] = u0.d;
    r.v[4] = u1.a; r.v[5] = u1.b; r.v[6] = u1.c; r.v[7] = u1.d;
    r.v[8] = p[8];
    return r;
}

__device__ __forceinline__ R6 load6(const float* __restrict__ p) {
    R6 r;
    F4s u = *(const F4s*)p;
    r.v[0] = u.a; r.v[1] = u.b; r.v[2] = u.c; r.v[3] = u.d;
    r.v[4] = p[4]; r.v[5] = p[5];
    return r;
}

__device__ __forceinline__ F3 load3(const float* __restrict__ p) {
    F3 r; r.x = p[0]; r.y = p[1]; r.z = p[2]; return r;
}

__device__ __forceinline__ F3 normal_of(const R9& r) {
    float e1x = r.v[0] - r.v[3], e1y = r.v[1] - r.v[4], e1z = r.v[2] - r.v[5];
    float e2x = r.v[0] - r.v[6], e2y = r.v[1] - r.v[7], e2z = r.v[2] - r.v[8];
    float nx = e1y * e2z - e1z * e2y;
    float ny = e1z * e2x - e1x * e2z;
    float nz = e1x * e2y - e1y * e2x;
    float inv = 1.0f / sqrtf(nx * nx + ny * ny + nz * nz);
    F3 o; o.x = nx * inv; o.y = ny * inv; o.z = nz * inv; return o;
}

__device__ __forceinline__ float tri_area(const F3& p, const F3& q, const F3& r) {
    float ax = q.x - p.x, ay = q.y - p.y, az = q.z - p.z;
    float bx = r.x - p.x, by = r.y - p.y, bz = r.z - p.z;
    float cx = ay * bz - az * by, cy = az * bx - ax * bz, cz = ax * by - ay * bx;
    return 0.5f * sqrtf(cx * cx + cy * cy + cz * cz);
}

__device__ __forceinline__ float edge_ew(const float* u1, const float* u2,
                                         const float* w1, const float* w2,
                                         const float* rA, const float* rB,
                                         const F3& n1, const F3& n2,
                                         const F3& pa, const F3& pb,
                                         float asum) {
    float ux = u1[0] - u2[0], uy = u1[1] - u2[1], uz = u1[2] - u2[2];
    float wx = w1[0] - w2[0], wy = w1[1] - w2[1], wz = w1[2] - w2[2];

    float d0 = rA[0] - rB[0], d1 = rA[1] - rB[1], d2 = rA[2] - rB[2];
    float d3 = rA[3] - rB[3], d4 = rA[4] - rB[4], d5 = rA[5] - rB[5];
    float d6 = rA[6] - rB[6], d7 = rA[7] - rB[7], d8 = rA[8] - rB[8];

    float ax = n1.x * d0 + n1.y * d3 + n1.z * d6;
    float ay = n1.x * d1 + n1.y * d4 + n1.z * d7;
    float az = n1.x * d2 + n1.y * d5 + n1.z * d8;
    float bx = n2.x * d0 + n2.y * d3 + n2.z * d6;
    float by = n2.x * d1 + n2.y * d4 + n2.z * d7;
    float bz = n2.x * d2 + n2.y * d5 + n2.z * d8;

    float uu = ux * ux + uy * uy + uz * uz;
    float ww = wx * wx + wy * wy + wz * wz;
    float uw = ux * wx + uy * wy + uz * wz;
    float aa = ax * ax + ay * ay + az * az;
    float bb = bx * bx + by * by + bz * bz;
    float ab = ax * bx + ay * by + az * bz;
    float energy = (3.0f * (uu + ww + uw) + (aa + bb + ab)) * (1.0f / 9.0f);

    float dx = pa.x - pb.x, dy = pa.y - pb.y, dz = pa.z - pb.z;
    return energy * (dx * dx + dy * dy + dz * dz) / asum;
}

__global__ __launch_bounds__(256) void fused_kernel(
        const float* __restrict__ tp,    // (2Q,3,3)
        const float* __restrict__ rot,   // (2Q,3,3)
        const float* __restrict__ verts, // (n*n,3)
        double* __restrict__ partials,
        int n) {
    const int m = n - 1;
    const int Q = m * m;
    const int tid = threadIdx.x;
    int q = blockIdx.x * 256 + tid;
    bool valid = q < Q;
    int qc = valid ? q : Q - 1;
    int i = qc / m;
    int j = qc - i * m;

    // ------------------- LOAD BATCH (no consumers here) -------------------
    int v00 = i * n + j;
    int iu = (i > 0) ? (i - 1) : 0;
    int jl = (j > 0) ? (j - 1) : 0;
    int f1  = i * m + j;
    int f2c = Q + f1;
    int f2u = Q + iu * m + j;       // tri2(i-1,j) (clamped; masked if i==0)
    int f2l = Q + i * m + jl;       // tri2(i,j-1) (clamped; masked if j==0)

    R9 tA = load9(tp + (size_t)9 * v00);            // vertex (i,j)
    R9 tB = load9(tp + (size_t)9 * (v00 + 1));      // vertex (i,j+1)
    R9 tC = load9(tp + (size_t)9 * (v00 + n));      // vertex (i+1,j)
    F3 p00 = load3(verts + (size_t)3 * v00);
    F3 p01 = load3(verts + (size_t)3 * (v00 + 1));
    F3 p10 = load3(verts + (size_t)3 * (v00 + n));
    F3 p11 = load3(verts + (size_t)3 * (v00 + n + 1));
    F3 pup = load3(verts + (size_t)3 * ((size_t)iu * n + (j + 1)));   // (i-1,j+1)
    F3 plf = load3(verts + (size_t)3 * ((size_t)(i + 1) * n + jl));   // (i+1,j-1)

    R9 t1 = load9(tp  + (size_t)9 * f1);
    R9 t2 = load9(tp  + (size_t)9 * f2c);
    R9 r1 = load9(rot + (size_t)9 * f1);
    R9 r2 = load9(rot + (size_t)9 * f2c);
    R6 th = load6(tp  + (size_t)9 * f2u);       // rows 0,1
    R9 rh = load9(rot + (size_t)9 * f2u);
    R6 tv = load6(tp  + (size_t)9 * f2l + 3);   // rows 1,2
    R9 rv = load9(rot + (size_t)9 * f2l);

    // Hard scheduling fence: nothing crosses. All ~43 VMEM loads above must
    // be issued (and their results allocated) before any compute below.
    __builtin_amdgcn_sched_barrier(0);

    // ------------------------- COMPUTE BATCH ------------------------------
    F3 nA = normal_of(tA);   // N[v00]
    F3 nB = normal_of(tB);   // N[v01]
    F3 nC = normal_of(tC);   // N[v10]
    float a1    = tri_area(p00, p10, p01);    // tri1(i,j)
    float a2c   = tri_area(p10, p11, p01);    // tri2(i,j)
    float a2up  = tri_area(p00, p01, pup);    // tri2(i-1,j): v10,v11,v01
    float a2lf  = tri_area(plf, p10, p00);    // tri2(i,j-1): v10,v11,v01

    float sum = edge_ew(t1.v + 6, t2.v + 6, t1.v + 3, t2.v + 0, r1.v, r2.v,
                        nB, nC, p01, p10, a1 + a2c);
    float eh = edge_ew(t1.v + 0, th.v + 0, t1.v + 6, th.v + 3, r1.v, rh.v,
                       nA, nB, p00, p01, a1 + a2up);
    float ev = edge_ew(t1.v + 0, tv.v + 3, t1.v + 3, tv.v + 0, r1.v, rv.v,
                       nA, nC, p00, p10, a1 + a2lf);
    sum += (i > 0 ? eh : 0.0f);
    sum += (j > 0 ? ev : 0.0f);

    double term = valid ? (double)sum : 0.0;

    // ---- block reduction ----
#pragma unroll
    for (int off = 32; off > 0; off >>= 1) term += __shfl_down(term, off, 64);
    __shared__ double sred[4];
    int lane = tid & 63, wid = tid >> 6;
    if (lane == 0) sred[wid] = term;
    __syncthreads();
    if (tid == 0)
        partials[blockIdx.x] = sred[0] + sred[1] + sred[2] + sred[3];
}

__global__ __launch_bounds__(256) void finalize_kernel(
        const double* __restrict__ partials, int P, float* __restrict__ out) {
    double s = 0.0;
    for (int i = threadIdx.x; i < P; i += 256) s += partials[i];
#pragma unroll
    for (int off = 32; off > 0; off >>= 1) s += __shfl_down(s, off, 64);
    __shared__ double sred[4];
    int lane = threadIdx.x & 63, wid = threadIdx.x >> 6;
    if (lane == 0) sred[wid] = s;
    __syncthreads();
    if (threadIdx.x == 0) out[0] = (float)(sred[0] + sred[1] + sred[2] + sred[3]);
}

extern "C" void kernel_launch(void* const* d_in, const int* in_sizes, int n_in,
                              void* d_out, int out_size, void* d_ws, size_t ws_size,
                              hipStream_t stream) {
    const float* tp    = (const float*)d_in[0];
    const float* rot   = (const float*)d_in[1];
    const float* verts = (const float*)d_in[2];

    int V = in_sizes[2] / 3;
    int n = (int)(sqrtf((float)V) + 0.5f);
    int m = n - 1;
    int Q = m * m;

    double* partials = (double*)d_ws;
    float*  out      = (float*)d_out;

    int P = (Q + 255) / 256;
    fused_kernel<<<P, 256, 0, stream>>>(tp, rot, verts, partials, n);
    finalize_kernel<<<1, 256, 0, stream>>>(partials, P, out);
}